// Round 3
// baseline (866.848 us; speedup 1.0000x reference)
//
#include <hip/hip_runtime.h>

// WaterNetModel — chunk-parallel exact scan.
//
// Recurrences per (site, hh):
//   snow:   s' = max(s - sm, 0) + p  = max(s + a, b), a = p - sm, b = p
//           (max-plus affine; composition (A,B)∘(a,b) = (A+a, max(B+a,b)) is associative)
//   linear: h' = (1-gl)(h + xin)     (affine; chunk summary h_out = cl^L h_in + hpart)
//
// Pipeline: K0 consts -> K1 per-chunk (A,B) -> K2 resolve s-boundaries (seq over NC)
//        -> K3 per-chunk hpart (needs s0) -> K4 resolve h-boundaries -> K5 final write.
// One thread per (site, chunk) in K1/K3/K5 holding all NH=16 hidden lanes in regs:
// P/T loads fully coalesced (fixes R1's 4x over-fetch), H/S stores float4 nontemporal,
// Q reduce in-register.

constexpr int NT = 1096;
constexpr int NS = 2048;
constexpr int NH = 16;
constexpr int NSH = NS * NH;

// Native vector type — __builtin_nontemporal_store rejects HIP_vector_type float4.
typedef float v4f __attribute__((ext_vector_type(4)));

// ---- K0: gate constants -> cst[64] = { mc[16], gi[16], gl[16], a[16] } ----
__global__ void k_const(const float* __restrict__ wi, const float* __restrict__ wo,
                        const float* __restrict__ wl, const float* __restrict__ wsb,
                        float* __restrict__ cst) {
    int j = threadIdx.x;
    if (j < NH) {
        cst[j]          = expf(wsb[j]) + 1.0f;           // melt_coef
        cst[NH + j]     = 1.0f / (1.0f + expf(-wi[j]));  // gi
        cst[2 * NH + j] = 1.0f / (1.0f + expf(-wl[j]));  // gl
        float mx = -1e30f;
        for (int k = 0; k < NH; ++k) mx = fmaxf(mx, wo[k]);
        float den = 0.0f;
        for (int k = 0; k < NH; ++k) den += expf(wo[k] - mx);
        cst[3 * NH + j] = expf(wo[j] - mx) / den;        // softmax a
    }
}

// ---- K1: per-chunk snow composition (A,B) ----
__global__ __launch_bounds__(256) void k_scanA(
    const float* __restrict__ P, const float* __restrict__ T,
    const float* __restrict__ cst, float* __restrict__ bufA, float* __restrict__ bufB,
    int NC, int L)
{
    const int gid = blockIdx.x * 256 + (int)threadIdx.x;   // 0 .. NS*NC-1
    const int site = gid & (NS - 1);
    const int c = gid >> 11;                               // NS = 2048 = 2^11
    if (c >= NC) return;

    float mc[NH];
    #pragma unroll
    for (int j = 0; j < NH; ++j) mc[j] = cst[j];

    float A[NH], B[NH];
    #pragma unroll
    for (int j = 0; j < NH; ++j) { A[j] = 0.0f; B[j] = -1e38f; }

    const int t0 = c * L;
    const int t1 = min(NT, t0 + L);
    float Pk = P[t0 * NS + site];
    float Tk = T[t0 * NS + site];
    for (int t = t0; t < t1; ++t) {
        float Pn = 0.0f, Tn = 0.0f;
        if (t + 1 < t1) { Pn = P[(t + 1) * NS + site]; Tn = T[(t + 1) * NS + site]; }
        const float tpos = fmaxf(Tk, 0.0f);
        const float pn = (Tk < 0.0f) ? Pk : 0.0f;
        #pragma unroll
        for (int j = 0; j < NH; ++j) {
            const float at = pn - tpos * mc[j];
            A[j] += at;
            B[j] = fmaxf(B[j] + at, pn);
        }
        Pk = Pn; Tk = Tn;
    }
    v4f* pa = (v4f*)(bufA + (size_t)c * NSH + site * NH);
    v4f* pb = (v4f*)(bufB + (size_t)c * NSH + site * NH);
    #pragma unroll
    for (int j = 0; j < 4; ++j) {
        v4f va = { A[4*j], A[4*j+1], A[4*j+2], A[4*j+3] };
        v4f vb = { B[4*j], B[4*j+1], B[4*j+2], B[4*j+3] };
        pa[j] = va; pb[j] = vb;
    }
}

// ---- K2: sequential resolve of chunk-boundary snow states (bufA: (A) -> s0) ----
__global__ __launch_bounds__(256) void k_resolveS(
    float* __restrict__ bufA, const float* __restrict__ bufB, int NC)
{
    const int idx = blockIdx.x * 256 + (int)threadIdx.x;   // 0 .. NSH-1
    float s = 0.0f;
    for (int c = 0; c < NC; ++c) {
        const size_t pos = (size_t)c * NSH + idx;
        const float a = bufA[pos];
        const float b = bufB[pos];
        bufA[pos] = s;                 // s0 entering chunk c
        s = fmaxf(s + a, b);
    }
}

// ---- K3: per-chunk h summary hpart (reads s0 from bufA, writes hpart to bufB) ----
__global__ __launch_bounds__(256) void k_scanH(
    const float* __restrict__ P, const float* __restrict__ T,
    const float* __restrict__ cst, const float* __restrict__ bufA,
    float* __restrict__ bufB, int NC, int L)
{
    const int gid = blockIdx.x * 256 + (int)threadIdx.x;
    const int site = gid & (NS - 1);
    const int c = gid >> 11;
    if (c >= NC) return;

    float mc[NH], gi[NH], cl[NH];
    #pragma unroll
    for (int j = 0; j < NH; ++j) {
        mc[j] = cst[j]; gi[j] = cst[NH + j]; cl[j] = 1.0f - cst[2 * NH + j];
    }

    float s[NH], hp[NH];
    const v4f* ps = (const v4f*)(bufA + (size_t)c * NSH + site * NH);
    #pragma unroll
    for (int j = 0; j < 4; ++j) {
        v4f v = ps[j];
        s[4*j] = v.x; s[4*j+1] = v.y; s[4*j+2] = v.z; s[4*j+3] = v.w;
        hp[4*j] = 0.0f; hp[4*j+1] = 0.0f; hp[4*j+2] = 0.0f; hp[4*j+3] = 0.0f;
    }

    const int t0 = c * L;
    const int t1 = min(NT, t0 + L);
    float Pk = P[t0 * NS + site];
    float Tk = T[t0 * NS + site];
    for (int t = t0; t < t1; ++t) {
        float Pn = 0.0f, Tn = 0.0f;
        if (t + 1 < t1) { Pn = P[(t + 1) * NS + site]; Tn = T[(t + 1) * NS + site]; }
        const float tpos = fmaxf(Tk, 0.0f);
        const float pn = (Tk < 0.0f) ? Pk : 0.0f;
        const float pp = (Tk > 0.0f) ? Pk : 0.0f;
        #pragma unroll
        for (int j = 0; j < NH; ++j) {
            const float sm = tpos * mc[j];
            const float m = fminf(sm, s[j]);
            s[j] = s[j] - m + pn;
            const float xin = (pp + m) * gi[j];
            hp[j] = cl[j] * (hp[j] + xin);
        }
        Pk = Pn; Tk = Tn;
    }
    v4f* pb = (v4f*)(bufB + (size_t)c * NSH + site * NH);
    #pragma unroll
    for (int j = 0; j < 4; ++j) {
        v4f v = { hp[4*j], hp[4*j+1], hp[4*j+2], hp[4*j+3] };
        pb[j] = v;
    }
}

// ---- K4: sequential resolve of chunk-boundary h states (bufB: hpart -> h0) ----
__global__ __launch_bounds__(256) void k_resolveH(
    const float* __restrict__ cst, float* __restrict__ bufB, int NC, int L, int Llast)
{
    const int idx = blockIdx.x * 256 + (int)threadIdx.x;   // 0 .. NSH-1
    const float gl = cst[2 * NH + (idx & (NH - 1))];
    const float cl = 1.0f - gl;
    const float clL = powf(cl, (float)L);
    const float clLast = powf(cl, (float)Llast);
    float h = 0.0f;
    for (int c = 0; c < NC; ++c) {
        const size_t pos = (size_t)c * NSH + idx;
        const float hp = bufB[pos];
        bufB[pos] = h;                 // h0 entering chunk c
        h = ((c == NC - 1) ? clLast : clL) * h + hp;
    }
}

// ---- K5: final recompute + write Q,H,S ----
__global__ __launch_bounds__(256) void k_final(
    const float* __restrict__ P, const float* __restrict__ T,
    const float* __restrict__ cst, const float* __restrict__ bufA,
    const float* __restrict__ bufB,
    float* __restrict__ Q, float* __restrict__ H, float* __restrict__ S,
    int NC, int L)
{
    const int gid = blockIdx.x * 256 + (int)threadIdx.x;
    const int site = gid & (NS - 1);
    const int c = gid >> 11;
    if (c >= NC) return;

    float mc[NH], gi[NH], gl[NH], aw[NH];
    #pragma unroll
    for (int j = 0; j < NH; ++j) {
        mc[j] = cst[j]; gi[j] = cst[NH + j]; gl[j] = cst[2 * NH + j]; aw[j] = cst[3 * NH + j];
    }

    float s[NH], h[NH];
    {
        const v4f* ps = (const v4f*)(bufA + (size_t)c * NSH + site * NH);
        const v4f* ph = (const v4f*)(bufB + (size_t)c * NSH + site * NH);
        #pragma unroll
        for (int j = 0; j < 4; ++j) {
            v4f vs = ps[j], vh = ph[j];
            s[4*j] = vs.x; s[4*j+1] = vs.y; s[4*j+2] = vs.z; s[4*j+3] = vs.w;
            h[4*j] = vh.x; h[4*j+1] = vh.y; h[4*j+2] = vh.z; h[4*j+3] = vh.w;
        }
    }

    const int t0 = c * L;
    const int t1 = min(NT, t0 + L);
    float Pk = P[t0 * NS + site];
    float Tk = T[t0 * NS + site];
    for (int t = t0; t < t1; ++t) {
        float Pn = 0.0f, Tn = 0.0f;
        if (t + 1 < t1) { Pn = P[(t + 1) * NS + site]; Tn = T[(t + 1) * NS + site]; }
        const float tpos = fmaxf(Tk, 0.0f);
        const float pn = (Tk < 0.0f) ? Pk : 0.0f;
        const float pp = (Tk > 0.0f) ? Pk : 0.0f;
        float qsum = 0.0f;
        #pragma unroll
        for (int j = 0; j < NH; ++j) {
            const float sm = tpos * mc[j];
            const float m = fminf(sm, s[j]);
            s[j] = s[j] - m + pn;
            const float xin = (pp + m) * gi[j];
            const float q = (xin + h[j]) * gl[j];
            h[j] = h[j] - q + xin;
            qsum += q * aw[j];
        }
        float* Sp = S + (size_t)t * NSH + site * NH;
        float* Hp = H + (size_t)t * NSH + site * NH;
        #pragma unroll
        for (int j = 0; j < 4; ++j) {
            v4f vs = { s[4*j], s[4*j+1], s[4*j+2], s[4*j+3] };
            v4f vh = { h[4*j], h[4*j+1], h[4*j+2], h[4*j+3] };
            __builtin_nontemporal_store(vs, (v4f*)Sp + j);
            __builtin_nontemporal_store(vh, (v4f*)Hp + j);
        }
        __builtin_nontemporal_store(qsum, Q + (size_t)t * NS + site);
        Pk = Pn; Tk = Tn;
    }
}

// ---- fallback: R1 monolithic sequential kernel (used only if ws too small) ----
__global__ __launch_bounds__(64) void waternet_seq(
    const float* __restrict__ P, const float* __restrict__ T,
    const float* __restrict__ w_i, const float* __restrict__ w_o,
    const float* __restrict__ w_l, const float* __restrict__ w_s,
    float* __restrict__ Q, float* __restrict__ H, float* __restrict__ S)
{
    const int gid = blockIdx.x * 64 + (int)threadIdx.x;
    const int hh = gid & (NH - 1);
    const int site = gid >> 4;
    const float melt_coef = expf(w_s[hh]) + 1.0f;
    const float gi = 1.0f / (1.0f + expf(-w_i[hh]));
    const float gl = 1.0f / (1.0f + expf(-w_l[hh]));
    float mx = -1e30f;
    for (int j = 0; j < NH; ++j) mx = fmaxf(mx, w_o[j]);
    float denom = 0.0f;
    for (int j = 0; j < NH; ++j) denom += expf(w_o[j] - mx);
    const float a = expf(w_o[hh] - mx) / denom;
    float s = 0.0f, h = 0.0f;
    for (int t = 0; t < NT; ++t) {
        const float Pk = P[t * NS + site];
        const float Tk = T[t * NS + site];
        const float sm = fmaxf(Tk, 0.0f) * melt_coef;
        const float m = fminf(sm, s);
        s = s - m + ((Tk < 0.0f) ? Pk : 0.0f);
        const float xin = (((Tk > 0.0f) ? Pk : 0.0f) + m) * gi;
        const float q = (xin + h) * gl;
        h = h - q + xin;
        const int ofs = t * NSH + gid;
        S[ofs] = s; H[ofs] = h;
        float qa = q * a;
        qa += __shfl_xor(qa, 1, 16);
        qa += __shfl_xor(qa, 2, 16);
        qa += __shfl_xor(qa, 4, 16);
        qa += __shfl_xor(qa, 8, 16);
        if (hh == 0) Q[t * NS + site] = qa;
    }
}

extern "C" void kernel_launch(void* const* d_in, const int* in_sizes, int n_in,
                              void* d_out, int out_size, void* d_ws, size_t ws_size,
                              hipStream_t stream) {
    const float* P   = (const float*)d_in[0];
    const float* T   = (const float*)d_in[1];
    const float* w_i = (const float*)d_in[2];
    const float* w_o = (const float*)d_in[3];
    const float* w_l = (const float*)d_in[4];
    const float* w_s = (const float*)d_in[5];

    float* Q = (float*)d_out;
    float* H = Q + (size_t)NT * NS;
    float* S = H + (size_t)NT * NS * NH;

    // Fallback if workspace can't hold even NC=1 (2 arrays of NSH + 64 consts).
    if (ws_size < 2ull * NSH * sizeof(float) + 256) {
        waternet_seq<<<(NS * NH) / 64, 64, 0, stream>>>(P, T, w_i, w_o, w_l, w_s, Q, H, S);
        return;
    }

    // Pick smallest chunk length L >= 8 whose scratch fits in ws_size.
    int L = 8, NC = (NT + L - 1) / L;
    for (;;) {
        NC = (NT + L - 1) / L;
        size_t need = 2ull * (size_t)NC * NSH * sizeof(float) + 256;
        if (need <= ws_size || NC == 1) break;
        ++L;
    }
    const int Llast = NT - (NC - 1) * L;

    float* bufA = (float*)d_ws;
    float* bufB = bufA + (size_t)NC * NSH;
    float* cst  = bufB + (size_t)NC * NSH;

    k_const<<<1, 64, 0, stream>>>(w_i, w_o, w_l, w_s, cst);

    const int nthr = NS * NC;
    const int nblk = (nthr + 255) / 256;
    const int rblk = (NSH + 255) / 256;

    k_scanA  <<<nblk, 256, 0, stream>>>(P, T, cst, bufA, bufB, NC, L);
    k_resolveS<<<rblk, 256, 0, stream>>>(bufA, bufB, NC);
    k_scanH  <<<nblk, 256, 0, stream>>>(P, T, cst, bufA, bufB, NC, L);
    k_resolveH<<<rblk, 256, 0, stream>>>(cst, bufB, NC, L, Llast);
    k_final  <<<nblk, 256, 0, stream>>>(P, T, cst, bufA, bufB, Q, H, S, NC, L);
}

// Round 4
// 417.202 us; speedup vs baseline: 2.0778x; 2.0778x over previous
//
#include <hip/hip_runtime.h>

// WaterNetModel — chunk-parallel exact scan, R4.
//
// R3 post-mortem: nontemporal strided stores caused 2.7x HBM write
// amplification (partial-line streaming writes); resolve kernels were
// latency-serialized by in-place read/write aliasing. R4: plain cached
// stores (L2 merges the 4 strided dwordx4 per line), 3-buffer ws layout
// with batched-prefetch resolves, constants computed per-thread (no k_const).
//
// Recurrences per (site, hh):
//   snow:   s' = max(s + a, b), a = p_neg - melt_pot, b = p_neg
//           composition (A,B)∘(a,b) = (A+a, max(B+a,b))  (associative)
//   linear: h' = cl*(h + xin), cl = 1-gl  -> chunk: h_out = cl^L h_in + hpart
//
// buf0 = A -> hpart ; buf1 = B -> h0 ; buf2 = s0.

constexpr int NT = 1096;
constexpr int NS = 2048;
constexpr int NH = 16;
constexpr int NSH = NS * NH;

typedef float v4f __attribute__((ext_vector_type(4)));

__device__ __forceinline__ float sigm(float x) { return 1.0f / (1.0f + expf(-x)); }

// ---- K1: per-chunk snow composition (A,B) ----
__global__ __launch_bounds__(256) void k_scanA(
    const float* __restrict__ P, const float* __restrict__ T,
    const float* __restrict__ wsb,
    float* __restrict__ outA, float* __restrict__ outB, int NC, int L)
{
    const int gid = blockIdx.x * 256 + (int)threadIdx.x;   // 0 .. NS*NC-1
    const int site = gid & (NS - 1);
    const int c = gid >> 11;                               // NS = 2048 = 2^11
    if (c >= NC) return;

    float mc[NH];
    #pragma unroll
    for (int j = 0; j < NH; ++j) mc[j] = expf(wsb[j]) + 1.0f;

    float A[NH], B[NH];
    #pragma unroll
    for (int j = 0; j < NH; ++j) { A[j] = 0.0f; B[j] = -1e38f; }

    const int t0 = c * L;
    const int t1 = min(NT, t0 + L);
    float Pk = P[t0 * NS + site];
    float Tk = T[t0 * NS + site];
    for (int t = t0; t < t1; ++t) {
        float Pn = 0.0f, Tn = 0.0f;
        if (t + 1 < t1) { Pn = P[(t + 1) * NS + site]; Tn = T[(t + 1) * NS + site]; }
        const float tpos = fmaxf(Tk, 0.0f);
        const float pn = (Tk < 0.0f) ? Pk : 0.0f;
        #pragma unroll
        for (int j = 0; j < NH; ++j) {
            const float at = pn - tpos * mc[j];
            A[j] += at;
            B[j] = fmaxf(B[j] + at, pn);
        }
        Pk = Pn; Tk = Tn;
    }
    v4f* pa = (v4f*)(outA + (size_t)c * NSH + site * NH);
    v4f* pb = (v4f*)(outB + (size_t)c * NSH + site * NH);
    #pragma unroll
    for (int j = 0; j < 4; ++j) {
        v4f va = { A[4*j], A[4*j+1], A[4*j+2], A[4*j+3] };
        v4f vb = { B[4*j], B[4*j+1], B[4*j+2], B[4*j+3] };
        pa[j] = va; pb[j] = vb;
    }
}

// ---- K2: resolve chunk-boundary snow states: (A,B) -> s0 (separate output) ----
__global__ __launch_bounds__(256) void k_resolveS(
    const float* __restrict__ A, const float* __restrict__ B,
    float* __restrict__ S0, int NC)
{
    const int idx = blockIdx.x * 256 + (int)threadIdx.x;   // 0 .. NSH-1
    float s = 0.0f;
    int c = 0;
    for (; c + 8 <= NC; c += 8) {
        float a[8], b[8];
        #pragma unroll
        for (int k = 0; k < 8; ++k) {
            const size_t pos = (size_t)(c + k) * NSH + idx;
            a[k] = A[pos]; b[k] = B[pos];
        }
        #pragma unroll
        for (int k = 0; k < 8; ++k) {
            S0[(size_t)(c + k) * NSH + idx] = s;
            s = fmaxf(s + a[k], b[k]);
        }
    }
    for (; c < NC; ++c) {
        const size_t pos = (size_t)c * NSH + idx;
        const float a = A[pos], b = B[pos];
        S0[pos] = s;
        s = fmaxf(s + a, b);
    }
}

// ---- K3: per-chunk h summary hpart (reads s0, writes hpart) ----
__global__ __launch_bounds__(256) void k_scanH(
    const float* __restrict__ P, const float* __restrict__ T,
    const float* __restrict__ wi, const float* __restrict__ wl,
    const float* __restrict__ wsb,
    const float* __restrict__ S0, float* __restrict__ HP, int NC, int L)
{
    const int gid = blockIdx.x * 256 + (int)threadIdx.x;
    const int site = gid & (NS - 1);
    const int c = gid >> 11;
    if (c >= NC) return;

    float mc[NH], gi[NH], cl[NH];
    #pragma unroll
    for (int j = 0; j < NH; ++j) {
        mc[j] = expf(wsb[j]) + 1.0f;
        gi[j] = sigm(wi[j]);
        cl[j] = 1.0f - sigm(wl[j]);
    }

    float s[NH], hp[NH];
    const v4f* ps = (const v4f*)(S0 + (size_t)c * NSH + site * NH);
    #pragma unroll
    for (int j = 0; j < 4; ++j) {
        v4f v = ps[j];
        s[4*j] = v.x; s[4*j+1] = v.y; s[4*j+2] = v.z; s[4*j+3] = v.w;
        hp[4*j] = 0.0f; hp[4*j+1] = 0.0f; hp[4*j+2] = 0.0f; hp[4*j+3] = 0.0f;
    }

    const int t0 = c * L;
    const int t1 = min(NT, t0 + L);
    float Pk = P[t0 * NS + site];
    float Tk = T[t0 * NS + site];
    for (int t = t0; t < t1; ++t) {
        float Pn = 0.0f, Tn = 0.0f;
        if (t + 1 < t1) { Pn = P[(t + 1) * NS + site]; Tn = T[(t + 1) * NS + site]; }
        const float tpos = fmaxf(Tk, 0.0f);
        const float pnn = (Tk < 0.0f) ? Pk : 0.0f;
        const float ppp = (Tk > 0.0f) ? Pk : 0.0f;
        #pragma unroll
        for (int j = 0; j < NH; ++j) {
            const float sm = tpos * mc[j];
            const float m = fminf(sm, s[j]);
            s[j] = s[j] - m + pnn;
            const float xin = (ppp + m) * gi[j];
            hp[j] = cl[j] * (hp[j] + xin);
        }
        Pk = Pn; Tk = Tn;
    }
    v4f* pb = (v4f*)(HP + (size_t)c * NSH + site * NH);
    #pragma unroll
    for (int j = 0; j < 4; ++j) {
        v4f v = { hp[4*j], hp[4*j+1], hp[4*j+2], hp[4*j+3] };
        pb[j] = v;
    }
}

// ---- K4: resolve chunk-boundary h states: hpart -> h0 (separate output) ----
__global__ __launch_bounds__(256) void k_resolveH(
    const float* __restrict__ wl, const float* __restrict__ HP,
    float* __restrict__ H0, int NC, int L, int Llast)
{
    const int idx = blockIdx.x * 256 + (int)threadIdx.x;   // 0 .. NSH-1
    const float cl = 1.0f - sigm(wl[idx & (NH - 1)]);
    const float clL = powf(cl, (float)L);
    const float clLast = powf(cl, (float)Llast);
    float h = 0.0f;
    int c = 0;
    for (; c + 8 <= NC; c += 8) {
        float hp[8];
        #pragma unroll
        for (int k = 0; k < 8; ++k) hp[k] = HP[(size_t)(c + k) * NSH + idx];
        #pragma unroll
        for (int k = 0; k < 8; ++k) {
            H0[(size_t)(c + k) * NSH + idx] = h;
            h = ((c + k == NC - 1) ? clLast : clL) * h + hp[k];
        }
    }
    for (; c < NC; ++c) {
        const size_t pos = (size_t)c * NSH + idx;
        const float hp = HP[pos];
        H0[pos] = h;
        h = ((c == NC - 1) ? clLast : clL) * h + hp;
    }
}

// ---- K5: final recompute + write Q,H,S (plain cached stores) ----
__global__ __launch_bounds__(256) void k_final(
    const float* __restrict__ P, const float* __restrict__ T,
    const float* __restrict__ wi, const float* __restrict__ wo,
    const float* __restrict__ wl, const float* __restrict__ wsb,
    const float* __restrict__ S0, const float* __restrict__ H0,
    float* __restrict__ Q, float* __restrict__ H, float* __restrict__ S,
    int NC, int L)
{
    const int gid = blockIdx.x * 256 + (int)threadIdx.x;
    const int site = gid & (NS - 1);
    const int c = gid >> 11;
    if (c >= NC) return;

    float mc[NH], gi[NH], gl[NH], aw[NH];
    {
        float mx = -1e30f;
        #pragma unroll
        for (int j = 0; j < NH; ++j) mx = fmaxf(mx, wo[j]);
        float den = 0.0f;
        #pragma unroll
        for (int j = 0; j < NH; ++j) den += expf(wo[j] - mx);
        #pragma unroll
        for (int j = 0; j < NH; ++j) {
            mc[j] = expf(wsb[j]) + 1.0f;
            gi[j] = sigm(wi[j]);
            gl[j] = sigm(wl[j]);
            aw[j] = expf(wo[j] - mx) / den;
        }
    }

    float s[NH], h[NH];
    {
        const v4f* ps = (const v4f*)(S0 + (size_t)c * NSH + site * NH);
        const v4f* ph = (const v4f*)(H0 + (size_t)c * NSH + site * NH);
        #pragma unroll
        for (int j = 0; j < 4; ++j) {
            v4f vs = ps[j], vh = ph[j];
            s[4*j] = vs.x; s[4*j+1] = vs.y; s[4*j+2] = vs.z; s[4*j+3] = vs.w;
            h[4*j] = vh.x; h[4*j+1] = vh.y; h[4*j+2] = vh.z; h[4*j+3] = vh.w;
        }
    }

    const int t0 = c * L;
    const int t1 = min(NT, t0 + L);
    float Pk = P[t0 * NS + site];
    float Tk = T[t0 * NS + site];
    for (int t = t0; t < t1; ++t) {
        float Pn = 0.0f, Tn = 0.0f;
        if (t + 1 < t1) { Pn = P[(t + 1) * NS + site]; Tn = T[(t + 1) * NS + site]; }
        const float tpos = fmaxf(Tk, 0.0f);
        const float pnn = (Tk < 0.0f) ? Pk : 0.0f;
        const float ppp = (Tk > 0.0f) ? Pk : 0.0f;
        float qsum = 0.0f;
        #pragma unroll
        for (int j = 0; j < NH; ++j) {
            const float sm = tpos * mc[j];
            const float m = fminf(sm, s[j]);
            s[j] = s[j] - m + pnn;
            const float xin = (ppp + m) * gi[j];
            const float q = (xin + h[j]) * gl[j];
            h[j] = h[j] - q + xin;
            qsum += q * aw[j];
        }
        v4f* Sp = (v4f*)(S + (size_t)t * NSH + site * NH);
        v4f* Hp = (v4f*)(H + (size_t)t * NSH + site * NH);
        #pragma unroll
        for (int j = 0; j < 4; ++j) {
            v4f vs = { s[4*j], s[4*j+1], s[4*j+2], s[4*j+3] };
            v4f vh = { h[4*j], h[4*j+1], h[4*j+2], h[4*j+3] };
            Sp[j] = vs;
            Hp[j] = vh;
        }
        Q[(size_t)t * NS + site] = qsum;
        Pk = Pn; Tk = Tn;
    }
}

// ---- fallback: monolithic sequential kernel (used only if ws too small) ----
__global__ __launch_bounds__(64) void waternet_seq(
    const float* __restrict__ P, const float* __restrict__ T,
    const float* __restrict__ w_i, const float* __restrict__ w_o,
    const float* __restrict__ w_l, const float* __restrict__ w_s,
    float* __restrict__ Q, float* __restrict__ H, float* __restrict__ S)
{
    const int gid = blockIdx.x * 64 + (int)threadIdx.x;
    const int hh = gid & (NH - 1);
    const int site = gid >> 4;
    const float melt_coef = expf(w_s[hh]) + 1.0f;
    const float gi = sigm(w_i[hh]);
    const float gl = sigm(w_l[hh]);
    float mx = -1e30f;
    for (int j = 0; j < NH; ++j) mx = fmaxf(mx, w_o[j]);
    float denom = 0.0f;
    for (int j = 0; j < NH; ++j) denom += expf(w_o[j] - mx);
    const float a = expf(w_o[hh] - mx) / denom;
    float s = 0.0f, h = 0.0f;
    for (int t = 0; t < NT; ++t) {
        const float Pk = P[t * NS + site];
        const float Tk = T[t * NS + site];
        const float sm = fmaxf(Tk, 0.0f) * melt_coef;
        const float m = fminf(sm, s);
        s = s - m + ((Tk < 0.0f) ? Pk : 0.0f);
        const float xin = (((Tk > 0.0f) ? Pk : 0.0f) + m) * gi;
        const float q = (xin + h) * gl;
        h = h - q + xin;
        const int ofs = t * NSH + gid;
        S[ofs] = s; H[ofs] = h;
        float qa = q * a;
        qa += __shfl_xor(qa, 1, 16);
        qa += __shfl_xor(qa, 2, 16);
        qa += __shfl_xor(qa, 4, 16);
        qa += __shfl_xor(qa, 8, 16);
        if (hh == 0) Q[t * NS + site] = qa;
    }
}

extern "C" void kernel_launch(void* const* d_in, const int* in_sizes, int n_in,
                              void* d_out, int out_size, void* d_ws, size_t ws_size,
                              hipStream_t stream) {
    const float* P   = (const float*)d_in[0];
    const float* T   = (const float*)d_in[1];
    const float* w_i = (const float*)d_in[2];
    const float* w_o = (const float*)d_in[3];
    const float* w_l = (const float*)d_in[4];
    const float* w_s = (const float*)d_in[5];

    float* Q = (float*)d_out;
    float* H = Q + (size_t)NT * NS;
    float* S = H + (size_t)NT * NS * NH;

    // Need 3 scratch arrays of NC*NSH floats. Fallback if even NC=1 won't fit.
    if (ws_size < 3ull * NSH * sizeof(float)) {
        waternet_seq<<<(NS * NH) / 64, 64, 0, stream>>>(P, T, w_i, w_o, w_l, w_s, Q, H, S);
        return;
    }

    // Smallest chunk length L >= 8 whose scratch fits in ws_size.
    int L = 8, NC;
    for (;;) {
        NC = (NT + L - 1) / L;
        size_t need = 3ull * (size_t)NC * NSH * sizeof(float);
        if (need <= ws_size || NC == 1) break;
        ++L;
    }
    const int Llast = NT - (NC - 1) * L;

    float* buf0 = (float*)d_ws;                 // A, then hpart
    float* buf1 = buf0 + (size_t)NC * NSH;      // B, then h0
    float* buf2 = buf1 + (size_t)NC * NSH;      // s0

    const int nblk = (NS * NC + 255) / 256;
    const int rblk = (NSH + 255) / 256;

    k_scanA   <<<nblk, 256, 0, stream>>>(P, T, w_s, buf0, buf1, NC, L);
    k_resolveS<<<rblk, 256, 0, stream>>>(buf0, buf1, buf2, NC);
    k_scanH   <<<nblk, 256, 0, stream>>>(P, T, w_i, w_l, w_s, buf2, buf0, NC, L);
    k_resolveH<<<rblk, 256, 0, stream>>>(w_l, buf0, buf1, NC, L, Llast);
    k_final   <<<nblk, 256, 0, stream>>>(P, T, w_i, w_o, w_l, w_s, buf2, buf1,
                                         Q, H, S, NC, L);
}